// Round 21
// baseline (640.387 us; speedup 1.0000x reference)
//
#include <hip/hip_runtime.h>
#include <hip/hip_bf16.h>

#define B_DIM 8192
#define IN_DIM 2048
#define H_DIM 2048
#define K_DIM 4096   // IN + H
#define N4H   8192   // 4*H
#define NT    64     // K tiles of BK=64

using short8 = __attribute__((ext_vector_type(8))) short;
using f32x4  = __attribute__((ext_vector_type(4))) float;
using u16x4  = __attribute__((ext_vector_type(4))) unsigned short;

__device__ __forceinline__ unsigned short f2bf(float f) {
  union { float f; unsigned int u; } v; v.f = f;
  unsigned int u = v.u;
  return (unsigned short)((u + 0x7FFFu + ((u >> 16) & 1u)) >> 16);
}

// ---------------------------------------------------------------------------
// pack_a: A_bf16[b][k] = bf16( k<2048 ? inp[b][k] : h0[b][k-2048] ), [8192][4096]
// ---------------------------------------------------------------------------
__global__ __launch_bounds__(256) void pack_a(const float* __restrict__ inp,
                                              const float* __restrict__ h0,
                                              unsigned short* __restrict__ Ap) {
  size_t idx = ((size_t)blockIdx.x * 256 + threadIdx.x) * 4;
  int b = (int)(idx >> 12);
  int k = (int)(idx & 4095);
  const float* src = (k < IN_DIM) ? (inp + (size_t)b * IN_DIM + k)
                                  : (h0  + (size_t)b * H_DIM + (k - IN_DIM));
  float4 v = *(const float4*)src;
  u16x4 o = { f2bf(v.x), f2bf(v.y), f2bf(v.z), f2bf(v.w) };
  *(u16x4*)&Ap[idx] = o;
}

// ---------------------------------------------------------------------------
// pack_b: B^T bf16 [8192 packed cols][4096 K], gate-interleaved columns.
// packed col c -> orig col = gate*2048 + j, gate=(c>>4)&3, j=(c>>6)*16+(c&15)
// ---------------------------------------------------------------------------
__global__ __launch_bounds__(256) void pack_b(const float* __restrict__ W,
                                              const float* __restrict__ U,
                                              unsigned short* __restrict__ Bp) {
  __shared__ float tile[64][17];
  const int c0 = blockIdx.x * 16;
  const int k0 = blockIdx.y * 64;
  const int gate  = (c0 >> 4) & 3;
  const int jbase = (c0 >> 6) * 16;
  const int colbase = gate * 2048 + jbase;
  const int t  = threadIdx.x;
  const int cc = t & 15;
  const int r0 = t >> 4;
#pragma unroll
  for (int rr = 0; rr < 4; ++rr) {
    int k = k0 + r0 + rr * 16;
    const float* src = (k < IN_DIM) ? (W + (size_t)k * N4H)
                                    : (U + (size_t)(k - IN_DIM) * N4H);
    tile[r0 + rr * 16][cc] = src[colbase + cc];
  }
  __syncthreads();
  const int c   = t >> 4;
  const int kk0 = (t & 15) * 4;
  u16x4 o = { f2bf(tile[kk0 + 0][c]), f2bf(tile[kk0 + 1][c]),
              f2bf(tile[kk0 + 2][c]), f2bf(tile[kk0 + 3][c]) };
  *(u16x4*)&Bp[(size_t)(c0 + c) * K_DIM + k0 + kk0] = o;
}

// ---------------------------------------------------------------------------
// Fused GEMM + LSTM epilogue. R20: 128x128 tile, BK=64, 4 waves (2x2),
// 64 KB LDS -> TWO blocks per CU = two independent barrier domains.
// Mechanism: R17's residual is ~1900 cyc/tile of sync stall; with one
// 8-wave block every barrier idles the whole CU. Two co-resident 4-wave
// blocks interleave freely — when block X drains, block Y issues MFMA
// (m114 cross-block overlap). Schedule is the R17 ledger verbatim:
//   q0: STAGE G0,G2(+1); RD af1(kt,1);                MFMA(0,af0)
//   q1: STAGE B0..B3(+1); VMCNT(6); bar; RD af0(kt,2); MFMA(1,af1)
//   q2: STAGE G1,G3(+1); RD af1(kt,3);                MFMA(2,af0)
//   q3: VMCNT(2); bar; RD af0(kt+1,0)[db]; {MFMA(3,af1) ∥ RD bf(kt+1)[db]}
// Granules (32 rows/cols x 64 k = 4 KB = one 256-thread STAGE issue):
//   A: G0=rows 0-31, G1=32-63, G2=64-95, G3=96-127. Wave wr reads
//   G(2wr) at phases 0-1, G(2wr+1) at phases 2-3 -> early set {G0,G2}
//   drained at q3(prev) [3-ph lead], late {G1,G3} at q1 [3-ph lead].
//   B: 4 col-granules, all read at q3(prev) after vmcnt(2) [2-ph lead].
// In-flight ledger: enter q0 with {G1,G3(kt)}=2; q0:+2; q1:+4=8, vmcnt(6)
// drains G1,G3(kt); q2:+2=8; q3: vmcnt(2) drains G0,G2,B0..B3(kt+1).
// WAR gaps all >=2 barriers (R17 audit carries over 1:1).
// Tail keeps vmcnt(0)+barrier before phase-2 reads [R5 race fix].
// Block map: xcd=wg&7, s=wg>>3, gen=s>>6, i=s&63;
//   bm=gen*8+(i>>3), bn=xcd*8+(i&7)  [bijective; 8x8 concurrent panels/XCD,
//   per-K-slice footprint ~256 KB -> L2-fits]
// LDS: buf*16384 elems + {A: row*64, B: 8192 + col*64}; 3-bit XOR swizzle
// (kgroup ^= row&7), pre-swizzled global source (linear LDS dest); bank
// math re-verified for this geometry (consec-8 -> 8 kgroups; stride-8 ->
// 4 groups x 2-way = free).
// ---------------------------------------------------------------------------
__global__ __launch_bounds__(256, 2) void lstm_gemm(
    const unsigned short* __restrict__ Ap,
    const unsigned short* __restrict__ Bp,
    const float* __restrict__ c0,
    const float* __restrict__ b_w,
    const float* __restrict__ b_u,
    float* __restrict__ out) {
  __shared__ unsigned short lds[32768];   // 64 KiB -> 2 blocks/CU

  const int t     = threadIdx.x;
  const int lane  = t & 63;
  const int wid   = t >> 6;     // 0..3
  const int wr    = wid >> 1;   // 0..1  (M half: rows wr*64)
  const int wc    = wid & 1;    // 0..1  (N half: cols wc*64)
  const int laneM = lane & 15;
  const int laneG = lane >> 4;  // 0..3

  // ---- square per-XCD footprint block map (bijective) ----
  const int wg  = blockIdx.x;
  const int xcd = wg & 7;
  const int s   = wg >> 3;      // 0..511
  const int gen = s >> 6;       // 0..7
  const int i   = s & 63;       // 0..63
  const int bm  = gen * 8 + (i >> 3);   // 0..63
  const int bn  = xcd * 8 + (i & 7);    // 0..63

  // ---- staging source (pre-swizzled global address, linear LDS dest) ----
  const int rt   = t >> 3;                 // 0..31 (row within 32-row granule)
  const int gt   = t & 7;                  // kgroup
  const int gsw  = gt ^ (rt & 7);          // 3-bit pre-swizzle
  const unsigned short* gA = Ap + (size_t)(bm * 128 + rt) * K_DIM + gsw * 8;
  const unsigned short* gB = Bp + (size_t)(bn * 128 + rt) * K_DIM + gsw * 8;

#define STAGE(gptr, ldsoff)                                                   \
  __builtin_amdgcn_global_load_lds(                                           \
      (const __attribute__((address_space(1))) void*)(gptr),                  \
      (__attribute__((address_space(3))) void*)&lds[(ldsoff) + t * 8], 16, 0, 0)

#define VMCNT(n) asm volatile("s_waitcnt vmcnt(" #n ")" ::: "memory")
#define BARF()                                                                \
  do {                                                                        \
    asm volatile("" ::: "memory");                                            \
    __builtin_amdgcn_s_barrier();                                             \
    asm volatile("" ::: "memory");                                            \
  } while (0)

  // ---- fragment read offsets (swizzled ds_read) ----
  const int sbit = laneM & 7;              // row&7
  int aoff[2], boff[2];
#pragma unroll
  for (int kk = 0; kk < 2; ++kk) {
    aoff[kk] = wr * 4096 + laneM * 64 + ((kk * 4 + laneG) ^ sbit) * 8;
    boff[kk] = 8192 + (wc * 64 + laneM) * 64 + ((kk * 4 + laneG) ^ sbit) * 8;
  }

  // phase PH (= m-frag) rows: wr*64 + PH*16 + laneM  -> aoff + PH*1024
#define RD_AF(AF, BASE, PH)                                                   \
  _Pragma("unroll")                                                           \
  for (int kk = 0; kk < 2; ++kk)                                              \
    AF[kk] = *(const short8*)&lds[(BASE) + aoff[kk] + (PH) * 1024];

#define RD_BF(BASE)                                                           \
  _Pragma("unroll")                                                           \
  for (int n = 0; n < 4; ++n)                                                 \
    _Pragma("unroll")                                                         \
    for (int kk = 0; kk < 2; ++kk)                                            \
      bfr[n][kk] = *(const short8*)&lds[(BASE) + boff[kk] + n * 1024];

#define MFMA8(Q, AF)                                                          \
  __builtin_amdgcn_s_setprio(1);                                              \
  _Pragma("unroll")                                                           \
  for (int n = 0; n < 4; ++n)                                                 \
    _Pragma("unroll")                                                         \
    for (int kk = 0; kk < 2; ++kk)                                            \
      acc[Q][n] = __builtin_amdgcn_mfma_f32_16x16x32_bf16(                    \
          AF[kk], bfr[n][kk], acc[Q][n], 0, 0, 0);                            \
  __builtin_amdgcn_s_setprio(0)

  // phase-3 cluster with next-tile B-reads interleaved per-n (R17 form)
#define MFMA8_Q3_RDB(DB)                                                      \
  __builtin_amdgcn_s_setprio(1);                                              \
  _Pragma("unroll")                                                           \
  for (int n = 0; n < 4; ++n) {                                               \
    _Pragma("unroll")                                                         \
    for (int kk = 0; kk < 2; ++kk)                                            \
      acc[3][n] = __builtin_amdgcn_mfma_f32_16x16x32_bf16(                    \
          af1[kk], bfr[n][kk], acc[3][n], 0, 0, 0);                           \
    _Pragma("unroll")                                                         \
    for (int kk = 0; kk < 2; ++kk)                                            \
      bfr[n][kk] = *(const short8*)&lds[(DB) + boff[kk] + n * 1024];          \
  }                                                                           \
  __builtin_amdgcn_s_setprio(0)

  f32x4 acc[4][4];
#pragma unroll
  for (int m = 0; m < 4; ++m)
#pragma unroll
    for (int n = 0; n < 4; ++n)
      acc[m][n] = (f32x4){0.f, 0.f, 0.f, 0.f};

  short8 af0[2], af1[2], bfr[4][2];

  // ---- bias preload, force-drained so the K-loop vmcnt ledger stays exact --
  const int j = (bn * 2 + wc) * 16 + laneM;
  float bias[4];
#pragma unroll
  for (int g = 0; g < 4; ++g)
    bias[g] = b_w[g * 2048 + j] + b_u[g * 2048 + j];
  asm volatile("s_waitcnt vmcnt(0)" ::: "memory");

  // ---- prologue: stage tile 0 in ledger order G0,G2 | B0..B3 | G1,G3 ----
  STAGE(gA,              0);            // G0: rows 0-31
  STAGE(gA + 64 * K_DIM, 4096);         // G2: rows 64-95
  STAGE(gB,              8192);         // B0: cols 0-31
  STAGE(gB + 32 * K_DIM, 8192 + 2048);  // B1
  STAGE(gB + 64 * K_DIM, 8192 + 4096);  // B2
  STAGE(gB + 96 * K_DIM, 8192 + 6144);  // B3
  STAGE(gA + 32 * K_DIM, 2048);         // G1: rows 32-63
  STAGE(gA + 96 * K_DIM, 6144);         // G3: rows 96-127
  VMCNT(2);               // drain G0,G2,B0..B3 ; leave {G1,G3}(0)
  BARF();
  RD_AF(af0, 0, 0);       // phase-0 A frags of tile 0
  RD_BF(0);               // all B frags of tile 0

  // ---- main loop: compute tile kt, stage tile kt+1 ----
#pragma unroll 1
  for (int kt = 0; kt < NT - 1; ++kt) {
    const int cb = (kt & 1) << 14;
    const int db = cb ^ 16384;
    const unsigned short* gA1 = gA + (kt + 1) * 64;
    const unsigned short* gB1 = gB + (kt + 1) * 64;
    // q0  (no barrier: G0,G2(kt) published at q3(kt-1); WAR gap >=2 bars)
    STAGE(gA1,              db + 0);
    STAGE(gA1 + 64 * K_DIM, db + 4096);
    RD_AF(af1, cb, 1);
    MFMA8(0, af0);
    // q1
    STAGE(gB1,              db + 8192);
    STAGE(gB1 + 32 * K_DIM, db + 8192 + 2048);
    STAGE(gB1 + 64 * K_DIM, db + 8192 + 4096);
    STAGE(gB1 + 96 * K_DIM, db + 8192 + 6144);
    VMCNT(6);               // drain G1,G3(kt)  [3-phase lead]
    BARF();
    RD_AF(af0, cb, 2);
    MFMA8(1, af1);
    // q2  (no barrier: G1,G3(kt) published at q1(kt); WAR gap >=2 bars)
    STAGE(gA1 + 32 * K_DIM, db + 2048);
    STAGE(gA1 + 96 * K_DIM, db + 6144);
    RD_AF(af1, cb, 3);
    MFMA8(2, af0);
    // q3
    VMCNT(2);               // drain G0,G2(+1) [3-ph], B0..B3(+1) [2-ph]
    BARF();
    RD_AF(af0, db, 0);      // phase-0 A frags of tile kt+1
    MFMA8_Q3_RDB(db);       // MFMA(3,af1) with bf(kt+1) reads interleaved
  }

  // ---- tail tile (NT-1), cb = 16384, no staging ----
  {
    RD_AF(af1, 16384, 1);
    MFMA8(0, af0);
    VMCNT(0);               // drain own G1,G3(63) slices...
    BARF();                 // ...and make OTHER waves' drained slices visible
    RD_AF(af0, 16384, 2);
    MFMA8(1, af1);
    RD_AF(af1, 16384, 3);
    MFMA8(2, af0);
    MFMA8(3, af1);
  }

  // ---- fused LSTM epilogue ----
  // packed col = bn*128 + wc*64 + n*16 + laneM -> gate = n, j = (bn*2+wc)*16+laneM
  const int rbase = bm * 128 + wr * 64 + laneG * 4;
  float* outH = out;
  float* outC = out + (size_t)B_DIM * H_DIM;
#pragma unroll
  for (int m = 0; m < 4; ++m) {
#pragma unroll
    for (int r = 0; r < 4; ++r) {
      const int bi = rbase + m * 16 + r;
      const size_t off = (size_t)bi * H_DIM + j;
      float ig = acc[m][0][r] + bias[0];
      float fg = acc[m][1][r] + bias[1];
      float og = acc[m][2][r] + bias[2];
      float gg = acc[m][3][r] + bias[3];
      float iv = 1.f / (1.f + __expf(-ig));
      float fv = 1.f / (1.f + __expf(-fg));
      float ov = 1.f / (1.f + __expf(-og));
      float gv = 2.f / (1.f + __expf(-2.f * gg)) - 1.f;
      float cv = fv * c0[off] + iv * gv;
      float tc = 2.f / (1.f + __expf(-2.f * cv)) - 1.f;
      outH[off] = ov * tc;
      outC[off] = cv;
    }
  }
}

// ---------------------------------------------------------------------------
extern "C" void kernel_launch(void* const* d_in, const int* in_sizes, int n_in,
                              void* d_out, int out_size, void* d_ws, size_t ws_size,
                              hipStream_t stream) {
  const float* inp = (const float*)d_in[0];
  const float* h0  = (const float*)d_in[1];
  const float* c0  = (const float*)d_in[2];
  const float* W   = (const float*)d_in[3];
  const float* b_w = (const float*)d_in[4];
  const float* U   = (const float*)d_in[5];
  const float* b_u = (const float*)d_in[6];
  float* out = (float*)d_out;

  unsigned short* Ap = (unsigned short*)d_ws;          // 64 MiB
  unsigned short* Bp = Ap + (size_t)B_DIM * K_DIM;     // +64 MiB

  pack_a<<<(B_DIM * K_DIM / 4) / 256, 256, 0, stream>>>(inp, h0, Ap);
  dim3 gb(N4H / 16, K_DIM / 64);
  pack_b<<<gb, 256, 0, stream>>>(W, U, Bp);
  lstm_gemm<<<4096, 256, 0, stream>>>(Ap, Bp, c0, b_w, b_u, out);
}

// Round 22
// 534.603 us; speedup vs baseline: 1.1979x; 1.1979x over previous
//
#include <hip/hip_runtime.h>
#include <hip/hip_bf16.h>

#define B_DIM 8192
#define IN_DIM 2048
#define H_DIM 2048
#define K_DIM 4096   // IN + H
#define N4H   8192   // 4*H
#define NT    64     // K tiles of BK=64

using short8 = __attribute__((ext_vector_type(8))) short;
using f32x4  = __attribute__((ext_vector_type(4))) float;
using u16x4  = __attribute__((ext_vector_type(4))) unsigned short;

__device__ __forceinline__ unsigned short f2bf(float f) {
  union { float f; unsigned int u; } v; v.f = f;
  unsigned int u = v.u;
  return (unsigned short)((u + 0x7FFFu + ((u >> 16) & 1u)) >> 16);
}

// ---------------------------------------------------------------------------
// pack_a: A_bf16[b][k] = bf16( k<2048 ? inp[b][k] : h0[b][k-2048] ), [8192][4096]
// ---------------------------------------------------------------------------
__global__ __launch_bounds__(256) void pack_a(const float* __restrict__ inp,
                                              const float* __restrict__ h0,
                                              unsigned short* __restrict__ Ap) {
  size_t idx = ((size_t)blockIdx.x * 256 + threadIdx.x) * 4;
  int b = (int)(idx >> 12);
  int k = (int)(idx & 4095);
  const float* src = (k < IN_DIM) ? (inp + (size_t)b * IN_DIM + k)
                                  : (h0  + (size_t)b * H_DIM + (k - IN_DIM));
  float4 v = *(const float4*)src;
  u16x4 o = { f2bf(v.x), f2bf(v.y), f2bf(v.z), f2bf(v.w) };
  *(u16x4*)&Ap[idx] = o;
}

// ---------------------------------------------------------------------------
// pack_b: B^T bf16 [8192 packed cols][4096 K], gate-interleaved columns.
// packed col c -> orig col = gate*2048 + j, gate=(c>>4)&3, j=(c>>6)*16+(c&15)
// ---------------------------------------------------------------------------
__global__ __launch_bounds__(256) void pack_b(const float* __restrict__ W,
                                              const float* __restrict__ U,
                                              unsigned short* __restrict__ Bp) {
  __shared__ float tile[64][17];
  const int c0 = blockIdx.x * 16;
  const int k0 = blockIdx.y * 64;
  const int gate  = (c0 >> 4) & 3;
  const int jbase = (c0 >> 6) * 16;
  const int colbase = gate * 2048 + jbase;
  const int t  = threadIdx.x;
  const int cc = t & 15;
  const int r0 = t >> 4;
#pragma unroll
  for (int rr = 0; rr < 4; ++rr) {
    int k = k0 + r0 + rr * 16;
    const float* src = (k < IN_DIM) ? (W + (size_t)k * N4H)
                                    : (U + (size_t)(k - IN_DIM) * N4H);
    tile[r0 + rr * 16][cc] = src[colbase + cc];
  }
  __syncthreads();
  const int c   = t >> 4;
  const int kk0 = (t & 15) * 4;
  u16x4 o = { f2bf(tile[kk0 + 0][c]), f2bf(tile[kk0 + 1][c]),
              f2bf(tile[kk0 + 2][c]), f2bf(tile[kk0 + 3][c]) };
  *(u16x4*)&Bp[(size_t)(c0 + c) * K_DIM + k0 + kk0] = o;
}

// ---------------------------------------------------------------------------
// Fused GEMM + LSTM epilogue, 256x256 tile, BK=64, 8 waves, MFMA 16x16x32.
// FINAL CHAMPION (R17; restored after R20's two-block experiment regressed):
// R14 schedule + R16 square per-XCD footprint + R17 q3 B-read interleave.
// Schedule: 2 barriers + 2 counted vmcnts per tile, read-ahead:
//   q0: STAGE A0,A2(+1); RD af1(kt,1);               MFMA(0,af0)
//   q1: STAGE B0..B3(+1); VMCNT(6); bar; RD af0(kt,2); MFMA(1,af1)
//   q2: STAGE A1,A3(+1); RD af1(kt,3);               MFMA(2,af0)
//   q3: VMCNT(2); bar; RD af0(kt+1,0)[db]; {MFMA(3,af1) ∥ RD bf(kt+1)[db]}
// Exhausted design matrix: sync count (1/2/4/8), drain (counted/full),
// staging (burst/2-4-2/4-4-0), read timing (ahead/current), MFMA shape
// (16x16/32x32), tile (128²/256²), barrier domains (1/2 blocks per CU) —
// R17 beat every neighbor. Counted drains with recent loads in flight
// are the key: vmcnt(6) [3-ph lead] + vmcnt(2) [2-3-ph leads].
// Block map (R16): xcd=wg&7, s=wg>>3, gen=s>>5, i=s&31;
//   bm=gen*8+(i>>2), bn=xcd*4+(i&3)  [bijective; 8x4 concurrent panels/XCD
//   -> L2-fits; FETCH 1.12 GB -> 0.44 GB measured]
// Visibility: af1(kt,1) reads A0/A2(kt) published q3(kt-1); af1(kt,3) reads
// A1/A3(kt) published q1(kt). WAR gaps all >=2 barriers (R14 audit).
// In-flight ledger (A0A2 | B0..B3 | A1A3): enter q0 with {A1A3(kt)}=2;
// q0:+2; q1:+4=8, vmcnt(6) drains A1A3(kt) [3-ph lead]; q2:+2=8;
// q3: vmcnt(2) drains A0A2(+1) [3-ph] + B0..B3(+1) [2-ph].
// Tail keeps vmcnt(0)+barrier before reading A1/A3(63)  [R5 race fix].
// LDS: buf*32768 + {A:0, B:16384}; 64-row units of [r][64], 3-bit XOR swizzle
// (kgroup ^= row&7), staged via pre-swizzled global source (linear LDS dest).
// Plateau note: MFMA pipe 56%, LDS ~45%, HBM 15% — structural local optimum
// of this family, not a hardware roofline.
// ---------------------------------------------------------------------------
__global__ __launch_bounds__(512, 2) void lstm_gemm(
    const unsigned short* __restrict__ Ap,
    const unsigned short* __restrict__ Bp,
    const float* __restrict__ c0,
    const float* __restrict__ b_w,
    const float* __restrict__ b_u,
    float* __restrict__ out) {
  __shared__ unsigned short lds[65536];   // 128 KiB

  const int t     = threadIdx.x;
  const int lane  = t & 63;
  const int wid   = t >> 6;     // 0..7
  const int wr    = wid >> 2;   // 0..1  (M half)
  const int wc    = wid & 3;    // 0..3  (N quarter)
  const int laneM = lane & 15;
  const int laneG = lane >> 4;  // 0..3

  // ---- square per-XCD footprint block map (bijective) ----
  const int wg  = blockIdx.x;
  const int xcd = wg & 7;
  const int s   = wg >> 3;      // 0..127 (per-XCD slot)
  const int gen = s >> 5;       // 0..3
  const int i   = s & 31;       // 0..31
  const int bm  = gen * 8 + (i >> 2);   // 0..31
  const int bn  = xcd * 4 + (i & 3);    // 0..31

  // ---- staging source (pre-swizzled global address, linear LDS dest) ----
  const int rt   = t >> 3;                 // 0..63 (row within 64-row unit)
  const int gt   = t & 7;                  // kgroup
  const int gsw  = gt ^ (rt & 7);          // 3-bit pre-swizzle
  const unsigned short* gA = Ap + (size_t)(bm * 256 + rt) * K_DIM + gsw * 8;
  const unsigned short* gB = Bp + (size_t)(bn * 256 + rt) * K_DIM + gsw * 8;

#define STAGE(gptr, ldsoff)                                                   \
  __builtin_amdgcn_global_load_lds(                                           \
      (const __attribute__((address_space(1))) void*)(gptr),                  \
      (__attribute__((address_space(3))) void*)&lds[(ldsoff) + t * 8], 16, 0, 0)

#define VMCNT(n) asm volatile("s_waitcnt vmcnt(" #n ")" ::: "memory")
#define BARF()                                                                \
  do {                                                                        \
    asm volatile("" ::: "memory");                                            \
    __builtin_amdgcn_s_barrier();                                             \
    asm volatile("" ::: "memory");                                            \
  } while (0)

  // ---- fragment read offsets (swizzled ds_read) ----
  const int sbit = laneM & 7;              // row&7
  int aoff[2], boff[2];
#pragma unroll
  for (int kk = 0; kk < 2; ++kk) {
    aoff[kk] = wr * 8192 + laneM * 64 + ((kk * 4 + laneG) ^ sbit) * 8;
    boff[kk] = 16384 + (wc >> 1) * 8192 + ((wc & 1) * 64 + laneM) * 64
               + ((kk * 4 + laneG) ^ sbit) * 8;
  }

#define RD_AF(AF, BASE, PH)                                                   \
  _Pragma("unroll")                                                           \
  for (int i_ = 0; i_ < 2; ++i_)                                              \
    _Pragma("unroll")                                                         \
    for (int kk = 0; kk < 2; ++kk)                                            \
      AF[i_][kk] = *(const short8*)&lds[(BASE) + aoff[kk] + (2 * (PH) + i_) * 1024];

#define RD_BF(BASE)                                                           \
  _Pragma("unroll")                                                           \
  for (int n = 0; n < 4; ++n)                                                 \
    _Pragma("unroll")                                                         \
    for (int kk = 0; kk < 2; ++kk)                                            \
      bfr[n][kk] = *(const short8*)&lds[(BASE) + boff[kk] + n * 1024];

#define MFMA16(Q, AF)                                                         \
  __builtin_amdgcn_s_setprio(1);                                              \
  _Pragma("unroll")                                                           \
  for (int i_ = 0; i_ < 2; ++i_)                                              \
    _Pragma("unroll")                                                         \
    for (int n = 0; n < 4; ++n)                                               \
      _Pragma("unroll")                                                       \
      for (int kk = 0; kk < 2; ++kk)                                          \
        acc[2 * (Q) + i_][n] = __builtin_amdgcn_mfma_f32_16x16x32_bf16(       \
            AF[i_][kk], bfr[n][kk], acc[2 * (Q) + i_][n], 0, 0, 0);           \
  __builtin_amdgcn_s_setprio(0)

  // phase-3 MFMA cluster with next-tile B-reads interleaved per-n:
  // after the 4 MFMAs consuming bfr[n], read next tile's bfr[n] (WAR ->
  // allocator renames; ds_reads issue inside the MFMA shadow).
#define MFMA16_Q3_RDB(DB)                                                     \
  __builtin_amdgcn_s_setprio(1);                                              \
  _Pragma("unroll")                                                           \
  for (int n = 0; n < 4; ++n) {                                               \
    _Pragma("unroll")                                                         \
    for (int i_ = 0; i_ < 2; ++i_)                                            \
      _Pragma("unroll")                                                       \
      for (int kk = 0; kk < 2; ++kk)                                          \
        acc[6 + i_][n] = __builtin_amdgcn_mfma_f32_16x16x32_bf16(             \
            af1[i_][kk], bfr[n][kk], acc[6 + i_][n], 0, 0, 0);                \
    _Pragma("unroll")                                                         \
    for (int kk = 0; kk < 2; ++kk)                                            \
      bfr[n][kk] = *(const short8*)&lds[(DB) + boff[kk] + n * 1024];          \
  }                                                                           \
  __builtin_amdgcn_s_setprio(0)

  f32x4 acc[8][4];
#pragma unroll
  for (int m = 0; m < 8; ++m)
#pragma unroll
    for (int n = 0; n < 4; ++n)
      acc[m][n] = (f32x4){0.f, 0.f, 0.f, 0.f};

  short8 af0[2][2], af1[2][2], bfr[4][2];

  // ---- bias preload, force-drained so the K-loop vmcnt ledger stays exact --
  const int j = (bn * 4 + wc) * 16 + laneM;
  float bias[4];
#pragma unroll
  for (int g = 0; g < 4; ++g)
    bias[g] = b_w[g * 2048 + j] + b_u[g * 2048 + j];
  asm volatile("s_waitcnt vmcnt(0)" ::: "memory");

  // ---- prologue: stage tile 0 in ledger order A0,A2,B0..B3,A1,A3 ----
  STAGE(gA,               0);
  STAGE(gA + 128 * K_DIM, 8192);
  STAGE(gB,               16384);
  STAGE(gB +  64 * K_DIM, 16384 + 4096);
  STAGE(gB + 128 * K_DIM, 16384 + 8192);
  STAGE(gB + 192 * K_DIM, 16384 + 12288);
  STAGE(gA +  64 * K_DIM, 4096);
  STAGE(gA + 192 * K_DIM, 12288);
  VMCNT(2);               // drain A0,A2,B0..B3 ; leave {A1,A3}(0)
  BARF();
  RD_AF(af0, 0, 0);       // phase-0 A frags of tile 0
  RD_BF(0);               // all B frags of tile 0

  // ---- main loop: compute tile kt, stage tile kt+1 ----
#pragma unroll 1
  for (int kt = 0; kt < NT - 1; ++kt) {
    const int cb = (kt & 1) << 15;
    const int db = cb ^ 32768;
    const unsigned short* gA1 = gA + (kt + 1) * 64;
    const unsigned short* gB1 = gB + (kt + 1) * 64;
    // q0  (no barrier: A0A2(kt) published at q3(kt-1); WAR gap >=2 bars)
    STAGE(gA1,               db + 0);
    STAGE(gA1 + 128 * K_DIM, db + 8192);
    RD_AF(af1, cb, 1);
    MFMA16(0, af0);
    // q1
    STAGE(gB1,               db + 16384);
    STAGE(gB1 +  64 * K_DIM, db + 16384 + 4096);
    STAGE(gB1 + 128 * K_DIM, db + 16384 + 8192);
    STAGE(gB1 + 192 * K_DIM, db + 16384 + 12288);
    VMCNT(6);               // drain A1,A3(kt)  [3-phase lead]
    BARF();
    RD_AF(af0, cb, 2);
    MFMA16(1, af1);
    // q2  (no barrier: A1A3(kt) published at q1(kt); WAR gap >=2 bars)
    STAGE(gA1 +  64 * K_DIM, db + 4096);
    STAGE(gA1 + 192 * K_DIM, db + 12288);
    RD_AF(af1, cb, 3);
    MFMA16(2, af0);
    // q3
    VMCNT(2);               // drain A0,A2(+1) [3-ph], B0..B3(+1) [2-ph]
    BARF();
    RD_AF(af0, db, 0);      // phase-0 A frags of tile kt+1
    MFMA16_Q3_RDB(db);      // MFMA(3,af1) with bf(kt+1) reads interleaved
  }

  // ---- tail tile (NT-1), cb = 32768, no staging ----
  {
    RD_AF(af1, 32768, 1);
    MFMA16(0, af0);
    VMCNT(0);               // drain own A1,A3(63) slices...
    BARF();                 // ...and make OTHER waves' drained slices visible
    RD_AF(af0, 32768, 2);
    MFMA16(1, af1);
    RD_AF(af1, 32768, 3);
    MFMA16(2, af0);
    MFMA16(3, af1);
  }

  // ---- fused LSTM epilogue ----
  // packed col = bn*256 + wc*64 + nn*16 + laneM -> gate = nn, j = (bn*4+wc)*16+laneM
  const int rbase = bm * 256 + wr * 128 + laneG * 4;
  float* outH = out;
  float* outC = out + (size_t)B_DIM * H_DIM;
#pragma unroll
  for (int m = 0; m < 8; ++m) {
#pragma unroll
    for (int r = 0; r < 4; ++r) {
      const int bi = rbase + m * 16 + r;
      const size_t off = (size_t)bi * H_DIM + j;
      float ig = acc[m][0][r] + bias[0];
      float fg = acc[m][1][r] + bias[1];
      float og = acc[m][2][r] + bias[2];
      float gg = acc[m][3][r] + bias[3];
      float iv = 1.f / (1.f + __expf(-ig));
      float fv = 1.f / (1.f + __expf(-fg));
      float ov = 1.f / (1.f + __expf(-og));
      float gv = 2.f / (1.f + __expf(-2.f * gg)) - 1.f;
      float cv = fv * c0[off] + iv * gv;
      float tc = 2.f / (1.f + __expf(-2.f * cv)) - 1.f;
      outH[off] = ov * tc;
      outC[off] = cv;
    }
  }
}

// ---------------------------------------------------------------------------
extern "C" void kernel_launch(void* const* d_in, const int* in_sizes, int n_in,
                              void* d_out, int out_size, void* d_ws, size_t ws_size,
                              hipStream_t stream) {
  const float* inp = (const float*)d_in[0];
  const float* h0  = (const float*)d_in[1];
  const float* c0  = (const float*)d_in[2];
  const float* W   = (const float*)d_in[3];
  const float* b_w = (const float*)d_in[4];
  const float* U   = (const float*)d_in[5];
  const float* b_u = (const float*)d_in[6];
  float* out = (float*)d_out;

  unsigned short* Ap = (unsigned short*)d_ws;          // 64 MiB
  unsigned short* Bp = Ap + (size_t)B_DIM * K_DIM;     // +64 MiB

  pack_a<<<(B_DIM * K_DIM / 4) / 256, 256, 0, stream>>>(inp, h0, Ap);
  dim3 gb(N4H / 16, K_DIM / 64);
  pack_b<<<gb, 256, 0, stream>>>(W, U, Bp);
  lstm_gemm<<<1024, 512, 0, stream>>>(Ap, Bp, c0, b_w, b_u, out);
}